// Round 9
// baseline (376.340 us; speedup 1.0000x reference)
//
#include <hip/hip_runtime.h>

#define B_ 256
#define T_ 2048
#define F_ 20
#define NT (B_*T_)
#define CH 16
#define NCH (T_/CH)   // 128 chunks

typedef __bf16 bf16x8 __attribute__((ext_vector_type(8)));
typedef float  f32x4  __attribute__((ext_vector_type(4)));

__device__ __forceinline__ float ex2(float x){ return __builtin_amdgcn_exp2f(x); }
__device__ __forceinline__ float rcpf_(float x){ return __builtin_amdgcn_rcpf(x); }

// 20*log2(e), 2*log2(e), log2(e)
#define K10F 28.853900817779268f
#define K1F   2.8853900817779268f
#define LOG2E 1.4426950408889634f

__device__ __forceinline__ float hside(float x){ return 1.0f - rcpf_(ex2(K10F*x) + 1.0f); }
__device__ __forceinline__ float tanh_f(float z){ return 1.0f - 2.0f*rcpf_(ex2(K1F*z) + 1.0f); }
__device__ __forceinline__ float sigmoid_f(float z){ return rcpf_(1.0f + ex2(-LOG2E*z)); }

// ws float layout (t-major r = t*256 + b):
// pp2 [0,2NT) float2{pet,p} | pk4 [2NT,6NT) float4{A,B,KP,_}

// ================= Kernel A: MLP (+pet/p gather) =================
__global__ __launch_bounds__(512) void mlp_kernel(const float* __restrict__ in,
    const float* __restrict__ w1, const float* __restrict__ b1,
    const float* __restrict__ w2, const float* __restrict__ b2,
    const float* __restrict__ w3, const float* __restrict__ b3,
    float* __restrict__ ws){
  __shared__ __bf16 w1f[16*32*8];
  __shared__ __bf16 w2f[32*64*8];
  __shared__ float  b1s[256];
  __shared__ float  b2s[64];
  __shared__ float  w3s[512];
  __shared__ float  b3s[8];
  __shared__ __bf16 hbufA[8*1152];

  float* pk4 = ws + 2*(size_t)NT;
  int tid = threadIdx.x;

  // gather pet/p for this block's 128 t-major rows (overlapped with staging)
  if (tid < 128){
    int r = blockIdx.x*128 + tid;
    int b = r & (B_-1), t = r >> 8;
    const float* src = in + ((size_t)b*T_ + t)*F_;
    ((float2*)ws)[r] = make_float2(src[0], src[2]);
  }

  for (int s = tid; s < 16*32*8; s += 512) w1f[s] = (__bf16)0.0f;
  __syncthreads();
  for (int idx = tid; idx < 15*256; idx += 512){   // w1: (k,n) k<15
    int k = idx >> 8, n = idx & 255;
    int ct = n >> 4;
    int l  = ((k>>3)*16) + (n & 15);
    int j  = k & 7;
    w1f[(ct*32 + l)*8 + j] = (__bf16)w1[idx];
  }
  for (int idx = tid; idx < 256*64; idx += 512){   // w2: (k,n)
    int k = idx >> 6, n = idx & 63;
    int kb = k >> 5;
    int lq = (k >> 3) & 3;
    int j  = k & 7;
    int ct = n >> 4;
    int l  = lq*16 + (n & 15);
    w2f[((kb*4 + ct)*64 + l)*8 + j] = (__bf16)w2[idx];
  }
  if (tid < 256) b1s[tid] = b1[tid];
  if (tid < 64)  b2s[tid] = b2[tid];
  if (tid < 512) w3s[tid] = w3[tid];
  if (tid < 8)   b3s[tid] = b3[tid];
  __syncthreads();

  int lane = tid & 63;
  int wv   = tid >> 6;
  int m    = lane & 15;
  int q    = lane >> 4;
  int r0   = blockIdx.x*128 + wv*16;   // t-major r

  int rowA = r0 + m;
  int bA = rowA & (B_-1), tA = rowA >> 8;
  const float* ap = in + ((size_t)bA*T_ + tA)*F_ + 5;
  bf16x8 a1;
  #pragma unroll
  for (int j = 0; j < 8; ++j){
    int k = q*8 + j;
    float v = (k < 15) ? ap[k] : 0.0f;
    a1[j] = (__bf16)v;
  }

  __bf16* hb = hbufA + wv*1152;
  f32x4 zero4 = {0.0f, 0.0f, 0.0f, 0.0f};
  bf16x8 zero8;
  #pragma unroll
  for (int j = 0; j < 8; ++j) zero8[j] = (__bf16)0.0f;

  f32x4 acc2[4] = {zero4, zero4, zero4, zero4};

  #pragma unroll
  for (int p = 0; p < 4; ++p){
    #pragma unroll
    for (int c4 = 0; c4 < 4; ++c4){
      int ct = p*4 + c4;
      bf16x8 bw = zero8;
      if (lane < 32) bw = *(const bf16x8*)&w1f[(ct*32 + lane)*8];
      f32x4 c1 = __builtin_amdgcn_mfma_f32_16x16x32_bf16(a1, bw, zero4, 0, 0, 0);
      int f = c4*16 + m;
      float bb = b1s[p*64 + f];
      #pragma unroll
      for (int i = 0; i < 4; ++i){
        float h = tanh_f(c1[i] + bb);
        hb[(q*4 + i)*72 + f] = (__bf16)h;
      }
    }
    #pragma unroll
    for (int kb = 0; kb < 2; ++kb){
      bf16x8 a2 = *(const bf16x8*)&hb[m*72 + q*8 + kb*32];
      #pragma unroll
      for (int ct = 0; ct < 4; ++ct){
        bf16x8 bw2 = *(const bf16x8*)&w2f[(((p*2 + kb)*4 + ct)*64 + lane)*8];
        acc2[ct] = __builtin_amdgcn_mfma_f32_16x16x32_bf16(a2, bw2, acc2[ct], 0, 0, 0);
      }
    }
  }

  #pragma unroll
  for (int ct = 0; ct < 4; ++ct){
    int f = ct*16 + m;
    float bb = b2s[f];
    #pragma unroll
    for (int i = 0; i < 4; ++i){
      float h = tanh_f(acc2[ct][i] + bb);
      hb[(q*4 + i)*72 + f] = (__bf16)h;
    }
  }

  float z0 = b3s[2*q], z1 = b3s[2*q + 1];
  #pragma unroll
  for (int kb3 = 0; kb3 < 8; ++kb3){
    bf16x8 hv8 = *(const bf16x8*)&hb[m*72 + kb3*8];
    #pragma unroll
    for (int j = 0; j < 8; ++j){
      float hv = (float)hv8[j];
      int k = kb3*8 + j;
      z0 = fmaf(hv, w3s[k*8 + 2*q],     z0);
      z1 = fmaf(hv, w3s[k*8 + 2*q + 1], z1);
    }
  }

  // reduce 8 params -> {A, B, KP} per row
  float* hf = (float*)hb;
  hf[m*8 + 2*q]     = sigmoid_f(z0);
  hf[m*8 + 2*q + 1] = sigmoid_f(z1);
  if (q == 0){
    float P0=hf[m*8+0], P1=hf[m*8+1], P2=hf[m*8+2], P3=hf[m*8+3];
    float P4=hf[m*8+4], P5=hf[m*8+5], P6=hf[m*8+6], P7=hf[m*8+7];
    // reference arg swap: _runoff(wu, wd, wl, p, wum, wdm, wlm, b, c)
    float wum = fmaf(P0, 19.9f, 0.1f);
    float wlm = fmaf(P2, 30.0f, 60.0f);
    float wdm = fmaf(P1, 60.0f, 60.0f);
    float wt  = wum + wlm + wdm;
    float rw  = 1.0f / wt;
    float cc  = fmaf(P4, 0.19f, 0.01f);
    float bc  = fmaf(P3, 0.30f, 0.10f);
    float A   = cc*rw*rw;
    float Bc  = bc*rw*rw;
    float k1  = fmaf(P5, 0.69f, 0.01f);
    float k2  = fmaf(P6, 0.69f, 0.01f);
    float k3  = fmaf(P7, 0.89f, 0.01f);
    float KP  = k1 + 0.5f*k2*(1.0f-k1) + 0.25f*k3*(1.0f-k1)*(1.0f-k2);
    int rowO = r0 + m;
    *(float4*)&pk4[(size_t)rowO*4] = make_float4(A, Bc, KP, 0.0f);
  }
}

// ================= Kernel B: scan + fused epilogue =================
// 4 blocks x 4 waves; LDS spin-flag pipeline (no __syncthreads => no vmcnt drains)
struct ScanB {
  float  d1L[2][CH][64];   // d1     W0 -> W1 (lag1)
  float  bsQ[4][CH][64];   // base   W0 -> W2 (lag2), W3 (lag3)
  float2 rhL[2][CH][64];   // rp,hrp W1 -> W2 (lag1)
  float2 qbL[2][CH][64];   // qv,b2  W2 -> W3 (lag1)
  int    done[4*16];
};

__global__ __launch_bounds__(256) void scan_kernel(const float* __restrict__ ws,
                                                   float* __restrict__ out){
  __shared__ ScanB S;
  const float2* pp2 = (const float2*)ws;
  const float*  pk4 = ws + 2*(size_t)NT;

  int tid  = threadIdx.x;
  int wv   = tid >> 6;
  int lane = tid & 63;
  int boff = blockIdx.x * 64;
  int bmy  = boff + lane;

  if (tid < 64) S.done[tid] = 0;
  __syncthreads();   // one-time init barrier

  auto publish = [&](int i, int v){
    if (lane == 0)
      __hip_atomic_store(&S.done[i*16], v, __ATOMIC_RELEASE, __HIP_MEMORY_SCOPE_WORKGROUP);
  };
  auto waitge = [&](int i, int v){
    while (__hip_atomic_load(&S.done[i*16], __ATOMIC_ACQUIRE, __HIP_MEMORY_SCOPE_WORKGROUP) < v)
      __builtin_amdgcn_s_sleep(1);
  };

  if (wv == 0){
    // -------- wu chain + pp2 prefetch --------
    float wu = 0.0f;
    float2 bufA[CH], bufB[CH];
    #pragma unroll
    for (int s = 0; s < CH; ++s) bufA[s] = pp2[s*B_ + bmy];
    #pragma unroll
    for (int s = 0; s < CH; ++s) bufB[s] = pp2[(CH + s)*B_ + bmy];

    for (int c = 0; c < NCH; c += 2){
      // ---- chunk c (bufA) ----
      waitge(1, c-1);
      waitge(3, c-3);
      #pragma unroll
      for (int s = 0; s < CH; ++s){
        float pet = bufA[s].x, p = bufA[s].y;
        float d  = wu - pet;
        float r1 = rcpf_(ex2(K10F*d) + 1.0f);
        float d1 = -d*r1;                       // pet - et1
        float base = (p - pet) + d1;            // p - et1
        wu += base;
        S.d1L[c&1][s][lane] = d1;
        S.bsQ[c&3][s][lane] = base;
      }
      publish(0, c+1);
      if (c + 2 < NCH){
        #pragma unroll
        for (int s = 0; s < CH; ++s) bufA[s] = pp2[((c+2)*CH + s)*B_ + bmy];
      }
      // ---- chunk c+1 (bufB) ----
      int c1 = c + 1;
      waitge(1, c1-1);
      waitge(3, c1-3);
      #pragma unroll
      for (int s = 0; s < CH; ++s){
        float pet = bufB[s].x, p = bufB[s].y;
        float d  = wu - pet;
        float r1 = rcpf_(ex2(K10F*d) + 1.0f);
        float d1 = -d*r1;
        float base = (p - pet) + d1;
        wu += base;
        S.d1L[c1&1][s][lane] = d1;
        S.bsQ[c1&3][s][lane] = base;
      }
      publish(0, c1+1);
      if (c1 + 2 < NCH){
        #pragma unroll
        for (int s = 0; s < CH; ++s) bufB[s] = pp2[((c1+2)*CH + s)*B_ + bmy];
      }
    }
  } else if (wv == 1){
    // -------- rp/hrp (stateless throughput) --------
    for (int c = 0; c < NCH; ++c){
      waitge(0, c+1);
      waitge(2, c-1);
      float d1_[CH];
      #pragma unroll
      for (int s = 0; s < CH; ++s) d1_[s] = S.d1L[c&1][s][lane];
      float2 rh_[CH];
      #pragma unroll
      for (int s = 0; s < CH; ++s){
        float r2 = rcpf_(ex2(K10F*d1_[s]) + 1.0f);
        float rp = fmaf(-d1_[s], r2, d1_[s]);
        float hrp = 1.0f - rcpf_(ex2(K10F*rp) + 1.0f);
        rh_[s] = make_float2(rp, hrp);
      }
      #pragma unroll
      for (int s = 0; s < CH; ++s) S.rhL[c&1][s][lane] = rh_[s];
      publish(1, c+1);
    }
  } else if (wv == 2){
    // -------- wl chain --------
    float wl = 0.0f;
    for (int c = 0; c < NCH; ++c){
      waitge(1, c+1);
      waitge(3, c-1);
      float2 rh_[CH]; float bs_[CH];
      #pragma unroll
      for (int s = 0; s < CH; ++s) rh_[s] = S.rhL[c&1][s][lane];
      #pragma unroll
      for (int s = 0; s < CH; ++s) bs_[s] = S.bsQ[c&3][s][lane];
      float2 qb_[CH];
      #pragma unroll
      for (int s = 0; s < CH; ++s){
        float d2   = rh_[s].x - wl;
        float r    = rcpf_(ex2(K10F*d2) + 1.0f);
        float et22 = fmaf(d2, r, wl);
        float et2  = rh_[s].y * et22;
        float b2   = bs_[s] - et2;
        wl += b2;
        qb_[s] = make_float2(rh_[s].x - et2, b2);
      }
      #pragma unroll
      for (int s = 0; s < CH; ++s) S.qbL[c&1][s][lane] = qb_[s];
      publish(2, c+1);
    }
  } else {
    // -------- wd chain + fused epilogue + direct out writes --------
    float wd = 0.0f, wu3 = 0.0f;
    for (int c = 0; c < NCH; ++c){
      waitge(2, c+1);
      // issue global loads first (latency covered by the chain)
      float4 k4_[CH]; float pv_[CH];
      #pragma unroll
      for (int s = 0; s < CH; ++s){
        int r = (c*CH + s)*B_ + bmy;
        k4_[s] = *(const float4*)&pk4[(size_t)r*4];
        pv_[s] = pp2[r].y;
      }
      float2 qb_[CH]; float bs_[CH];
      #pragma unroll
      for (int s = 0; s < CH; ++s) qb_[s] = S.qbL[c&1][s][lane];
      #pragma unroll
      for (int s = 0; s < CH; ++s) bs_[s] = S.bsQ[c&3][s][lane];
      float qv_[CH];
      #pragma unroll
      for (int s = 0; s < CH; ++s){
        float hqv  = 1.0f - rcpf_(ex2(K10F*qb_[s].x) + 1.0f);
        float d3   = qb_[s].x - wd;
        float r    = rcpf_(ex2(K10F*d3) + 1.0f);
        float et33 = fmaf(d3, r, wd);
        float et3  = hqv * et33;
        wd += qb_[s].y - et3;
        wu3 += bs_[s];                       // bit-identical replay of wave0's wu
        float ps = pv_[s] - k4_[s].x*wu3*wu3 - k4_[s].y*wd*wd;
        float runoff = hside(ps)*ps;
        qv_[s] = k4_[s].z * runoff;
      }
      publish(3, c+1);
      float* dst = out + (size_t)bmy*T_ + c*CH;   // one full 64B line per lane
      #pragma unroll
      for (int g = 0; g < 4; ++g)
        *(float4*)(dst + g*4) = make_float4(qv_[g*4], qv_[g*4+1], qv_[g*4+2], qv_[g*4+3]);
    }
  }
}

extern "C" void kernel_launch(void* const* d_in, const int* in_sizes, int n_in,
                              void* d_out, int out_size, void* d_ws, size_t ws_size,
                              hipStream_t stream) {
  const float* in = (const float*)d_in[0];
  const float* w1 = (const float*)d_in[1];
  const float* b1 = (const float*)d_in[2];
  const float* w2 = (const float*)d_in[3];
  const float* b2 = (const float*)d_in[4];
  const float* w3 = (const float*)d_in[5];
  const float* b3 = (const float*)d_in[6];
  float* out = (float*)d_out;
  float* ws  = (float*)d_ws;

  mlp_kernel <<<NT/128, 512, 0, stream>>>(in, w1, b1, w2, b2, w3, b3, ws);
  scan_kernel<<<4,      256, 0, stream>>>(ws, out);
}

// Round 10
// 301.872 us; speedup vs baseline: 1.2467x; 1.2467x over previous
//
#include <hip/hip_runtime.h>

#define B_ 256
#define T_ 2048
#define F_ 20
#define NT (B_*T_)
#define CH 16
#define NCH (T_/CH)   // 128 chunks

typedef __bf16 bf16x8 __attribute__((ext_vector_type(8)));
typedef float  f32x4  __attribute__((ext_vector_type(4)));

__device__ __forceinline__ float ex2(float x){ return __builtin_amdgcn_exp2f(x); }
__device__ __forceinline__ float rcpf_(float x){ return __builtin_amdgcn_rcpf(x); }

// 20*log2(e), 2*log2(e), log2(e), ln2/20
#define K10F 28.853900817779268f
#define INVK 0.034657359027997264f
#define K1F   2.8853900817779268f
#define LOG2E 1.4426950408889634f

__device__ __forceinline__ float hside(float x){ return 1.0f - rcpf_(ex2(K10F*x) + 1.0f); }
__device__ __forceinline__ float tanh_f(float z){ return 1.0f - 2.0f*rcpf_(ex2(K1F*z) + 1.0f); }
__device__ __forceinline__ float sigmoid_f(float z){ return rcpf_(1.0f + ex2(-LOG2E*z)); }

// ws float layout (t-major r = t*256 + b):
// wuT [0,NT) | wdT [NT,2NT) | pk4 [2NT,6NT) float4{A,B,KP,_} | pT [6NT,7NT)

// Scan rings: [ring][lane][step] with padded step dim => per-lane contiguous
// (consumers batch-read via b64) and 2-way-max bank aliasing (free).
struct ScanS {
  float  dkR[2][64][18];   // dK    W0 -> W1 (lag1)       9216 B
  float  bsQ[4][64][18];   // BASE  W0 -> W2 (lag2)      18432 B
  float2 rhR[2][64][17];   // RP,HRP W1 -> W2 (lag1)     17408 B
  float2 qbR[2][64][17];   // QV,B2  W2 -> W3 (lag1)     17408 B
};
struct MlpS {
  __bf16 w1f[16*32*8];     //  8192 B
  __bf16 w2f[32*64*8];     // 32768 B
  float  b1s[256];
  float  b2s[64];
  float  w3s[512];
  float  b3s[8];
  __bf16 hbuf[8][1152];    // 18432 B
};
union SMu { ScanS s; MlpS m; };

// blocks 0..3: pipelined scan (64 batches each; waves 0-3 = stages, 4-7 barrier-only)
// blocks 4..515: MFMA MLP, grid-stride 8 row-tiles of 128 per block
__global__ __launch_bounds__(512) void fused_kernel(const float* __restrict__ in,
    const float* __restrict__ w1, const float* __restrict__ b1,
    const float* __restrict__ w2, const float* __restrict__ b2,
    const float* __restrict__ w3, const float* __restrict__ b3,
    float* __restrict__ ws){
  __shared__ SMu smu;
  float* pk4 = ws + 2*(size_t)NT;

  if (blockIdx.x < 4) {
    // ================== K-scaled pipelined scan ==================
    asm volatile("s_setprio 3");
    ScanS& S = smu.s;
    float* wuT = ws;
    float* wdT = ws + (size_t)NT;
    float* pT  = ws + 6*(size_t)NT;
    int tid  = threadIdx.x;
    int wv   = tid >> 6;
    int lane = tid & 63;
    int bmy  = blockIdx.x*64 + lane;
    const float* inb = in + (size_t)bmy*T_*F_;

    if (wv == 0){
      // -------- wu chain + direct global loads + wuT/pT stores --------
      float Ape[CH], Ap[CH], Bpe[CH], Bp[CH];
      #pragma unroll
      for (int s = 0; s < CH; ++s){ Ape[s] = inb[(size_t)s*F_]; Ap[s] = inb[(size_t)s*F_ + 2]; }
      float Wu = 0.0f;
      for (int it = 0; it < NCH + 3; ++it){
        int c = it;
        if (c < NCH){
          if (c + 1 < NCH){
            #pragma unroll
            for (int s = 0; s < CH; ++s){
              Bpe[s] = inb[(size_t)((c+1)*CH + s)*F_];
              Bp[s]  = inb[(size_t)((c+1)*CH + s)*F_ + 2];
            }
          }
          #pragma unroll
          for (int s = 0; s < CH; ++s){
            float pet = Ape[s], p = Ap[s];
            float PET = K10F*pet;
            float PPd = K10F*(p - pet);
            float t1  = Wu - PET;
            float r   = rcpf_(ex2(t1) + 1.0f);
            float dK  = -t1*r;
            float BS  = PPd + dK;
            Wu += BS;
            S.dkR[c&1][lane][s] = dK;
            S.bsQ[c&3][lane][s] = BS;
            wuT[(c*CH + s)*B_ + bmy] = Wu * INVK;
            pT [(c*CH + s)*B_ + bmy] = p;
          }
          if (c + 1 < NCH){
            #pragma unroll
            for (int s = 0; s < CH; ++s){ Ape[s] = Bpe[s]; Ap[s] = Bp[s]; }
          }
        }
        __syncthreads();
      }
    } else if (wv == 1){
      // -------- stateless RP/HRP --------
      for (int it = 0; it < NCH + 3; ++it){
        int c = it - 1;
        if (c >= 0 && c < NCH){
          float dk_[CH];
          #pragma unroll
          for (int k = 0; k < CH/2; ++k)
            *(float2*)&dk_[2*k] = *(const float2*)&S.dkR[c&1][lane][2*k];
          float2 rh_[CH];
          #pragma unroll
          for (int s = 0; s < CH; ++s){
            float r1  = rcpf_(ex2(dk_[s]) + 1.0f);
            float RP  = fmaf(-dk_[s], r1, dk_[s]);
            float HRP = 1.0f - rcpf_(ex2(RP) + 1.0f);
            rh_[s] = make_float2(RP, HRP);
          }
          #pragma unroll
          for (int s = 0; s < CH; ++s) S.rhR[c&1][lane][s] = rh_[s];
        }
        __syncthreads();
      }
    } else if (wv == 2){
      // -------- wl chain --------
      float WL = 0.0f;
      for (int it = 0; it < NCH + 3; ++it){
        int c = it - 2;
        if (c >= 0 && c < NCH){
          float2 rh_[CH];
          #pragma unroll
          for (int s = 0; s < CH; ++s) rh_[s] = S.rhR[c&1][lane][s];
          float bs_[CH];
          #pragma unroll
          for (int k = 0; k < CH/2; ++k)
            *(float2*)&bs_[2*k] = *(const float2*)&S.bsQ[c&3][lane][2*k];
          float2 qb_[CH];
          #pragma unroll
          for (int s = 0; s < CH; ++s){
            float D2   = rh_[s].x - WL;
            float r    = rcpf_(ex2(D2) + 1.0f);
            float et22 = fmaf(D2, r, WL);
            float ET2  = rh_[s].y * et22;
            float WLB  = WL + bs_[s];
            WL = fmaf(-rh_[s].y, et22, WLB);
            qb_[s] = make_float2(rh_[s].x - ET2, bs_[s] - ET2);
          }
          #pragma unroll
          for (int s = 0; s < CH; ++s) S.qbR[c&1][lane][s] = qb_[s];
        }
        __syncthreads();
      }
    } else if (wv == 3){
      // -------- wd chain + wdT stores --------
      float WD = 0.0f;
      for (int it = 0; it < NCH + 3; ++it){
        int c = it - 3;
        if (c >= 0){
          float2 qb_[CH];
          #pragma unroll
          for (int s = 0; s < CH; ++s) qb_[s] = S.qbR[c&1][lane][s];
          #pragma unroll
          for (int s = 0; s < CH; ++s){
            float HQ   = 1.0f - rcpf_(ex2(qb_[s].x) + 1.0f);
            float D3   = qb_[s].x - WD;
            float r    = rcpf_(ex2(D3) + 1.0f);
            float et33 = fmaf(D3, r, WD);
            float WDB  = WD + qb_[s].y;
            WD = fmaf(-HQ, et33, WDB);
            wdT[(c*CH + s)*B_ + bmy] = WD * INVK;
          }
        }
        __syncthreads();
      }
    } else {
      for (int it = 0; it < NCH + 3; ++it) __syncthreads();
    }
    return;
  }

  // ================== MFMA MLP path: stage once, 8 row-tiles ==================
  MlpS& M = smu.m;
  int tid = threadIdx.x;

  for (int s = tid; s < 16*32*8; s += 512) M.w1f[s] = (__bf16)0.0f;
  __syncthreads();
  for (int idx = tid; idx < 15*256; idx += 512){   // w1: (k,n) k<15
    int k = idx >> 8, n = idx & 255;
    int ct = n >> 4;
    int l  = ((k>>3)*16) + (n & 15);
    int j  = k & 7;
    M.w1f[(ct*32 + l)*8 + j] = (__bf16)w1[idx];
  }
  for (int idx = tid; idx < 256*64; idx += 512){   // w2: (k,n)
    int k = idx >> 6, n = idx & 63;
    int kb = k >> 5;
    int lq = (k >> 3) & 3;
    int j  = k & 7;
    int ct = n >> 4;
    int l  = lq*16 + (n & 15);
    M.w2f[((kb*4 + ct)*64 + l)*8 + j] = (__bf16)w2[idx];
  }
  if (tid < 256) M.b1s[tid] = b1[tid];
  if (tid < 64)  M.b2s[tid] = b2[tid];
  if (tid < 512) M.w3s[tid] = w3[tid];
  if (tid < 8)   M.b3s[tid] = b3[tid];
  __syncthreads();

  int lane = tid & 63;
  int wv   = tid >> 6;
  int m    = lane & 15;
  int q    = lane >> 4;
  __bf16* hb = M.hbuf[wv];
  f32x4 zero4 = {0.0f, 0.0f, 0.0f, 0.0f};
  bf16x8 zero8;
  #pragma unroll
  for (int j = 0; j < 8; ++j) zero8[j] = (__bf16)0.0f;

  for (int g = 0; g < 8; ++g){
    int r0  = (blockIdx.x - 4)*128 + g*65536 + wv*16;   // t-major row base
    int rho = r0 + m;
    const float* ap = in + (size_t)rho*F_ + 5;
    bf16x8 a1;
    #pragma unroll
    for (int j = 0; j < 8; ++j){
      int k = q*8 + j;
      float v = (k < 15) ? ap[k] : 0.0f;
      a1[j] = (__bf16)v;
    }

    f32x4 acc2[4] = {zero4, zero4, zero4, zero4};

    #pragma unroll
    for (int p = 0; p < 4; ++p){
      #pragma unroll
      for (int c4 = 0; c4 < 4; ++c4){
        int ct = p*4 + c4;
        bf16x8 bw = zero8;
        if (lane < 32) bw = *(const bf16x8*)&M.w1f[(ct*32 + lane)*8];
        f32x4 c1 = __builtin_amdgcn_mfma_f32_16x16x32_bf16(a1, bw, zero4, 0, 0, 0);
        int f = c4*16 + m;
        float bb = M.b1s[p*64 + f];
        #pragma unroll
        for (int i = 0; i < 4; ++i){
          float h = tanh_f(c1[i] + bb);
          hb[(q*4 + i)*72 + f] = (__bf16)h;
        }
      }
      #pragma unroll
      for (int kb = 0; kb < 2; ++kb){
        bf16x8 a2 = *(const bf16x8*)&hb[m*72 + q*8 + kb*32];
        #pragma unroll
        for (int ct = 0; ct < 4; ++ct){
          bf16x8 bw2 = *(const bf16x8*)&M.w2f[(((p*2 + kb)*4 + ct)*64 + lane)*8];
          acc2[ct] = __builtin_amdgcn_mfma_f32_16x16x32_bf16(a2, bw2, acc2[ct], 0, 0, 0);
        }
      }
    }

    #pragma unroll
    for (int ct = 0; ct < 4; ++ct){
      int f = ct*16 + m;
      float bb = M.b2s[f];
      #pragma unroll
      for (int i = 0; i < 4; ++i){
        float h = tanh_f(acc2[ct][i] + bb);
        hb[(q*4 + i)*72 + f] = (__bf16)h;
      }
    }

    float z0 = M.b3s[2*q], z1 = M.b3s[2*q + 1];
    #pragma unroll
    for (int kb3 = 0; kb3 < 8; ++kb3){
      bf16x8 hv8 = *(const bf16x8*)&hb[m*72 + kb3*8];
      #pragma unroll
      for (int j = 0; j < 8; ++j){
        float hv = (float)hv8[j];
        int k = kb3*8 + j;
        z0 = fmaf(hv, M.w3s[k*8 + 2*q],     z0);
        z1 = fmaf(hv, M.w3s[k*8 + 2*q + 1], z1);
      }
    }

    // reduce 8 params -> {A, B, KP} per row (same-wave LDS scratch)
    float* hf = (float*)hb;
    hf[m*8 + 2*q]     = sigmoid_f(z0);
    hf[m*8 + 2*q + 1] = sigmoid_f(z1);
    if (q == 0){
      float P0=hf[m*8+0], P1=hf[m*8+1], P2=hf[m*8+2], P3=hf[m*8+3];
      float P4=hf[m*8+4], P5=hf[m*8+5], P6=hf[m*8+6], P7=hf[m*8+7];
      // reference arg swap: _runoff(wu, wd, wl, p, wum, wdm, wlm, b, c)
      float wum = fmaf(P0, 19.9f, 0.1f);
      float wlm = fmaf(P2, 30.0f, 60.0f);
      float wdm = fmaf(P1, 60.0f, 60.0f);
      float wt  = wum + wlm + wdm;
      float rw  = 1.0f / wt;
      float cc  = fmaf(P4, 0.19f, 0.01f);
      float bc  = fmaf(P3, 0.30f, 0.10f);
      float A   = cc*rw*rw;
      float Bc  = bc*rw*rw;
      float k1  = fmaf(P5, 0.69f, 0.01f);
      float k2  = fmaf(P6, 0.69f, 0.01f);
      float k3  = fmaf(P7, 0.89f, 0.01f);
      float KP  = k1 + 0.5f*k2*(1.0f-k1) + 0.25f*k3*(1.0f-k1)*(1.0f-k2);
      *(float4*)&pk4[(size_t)rho*4] = make_float4(A, Bc, KP, 0.0f);
    }
  }
}

// 64t × 64b tile; coalesced reads of t-major arrays, LDS transpose, coalesced out-writes
__global__ __launch_bounds__(256) void final_kernel(const float* __restrict__ ws,
                                                    float* __restrict__ out){
  __shared__ float tile[64*65];
  int tb = blockIdx.x & 31;
  int bb = blockIdx.x >> 5;
  int t0 = tb*64, b0 = bb*64;
  int tid = threadIdx.x;
  const float* wuT = ws;
  const float* wdT = ws + (size_t)NT;
  const float* pk4 = ws + 2*(size_t)NT;
  const float* pT  = ws + 6*(size_t)NT;

  #pragma unroll
  for (int k = 0; k < 16; ++k){
    int idx = k*256 + tid;
    int tl = idx >> 6, bl = idx & 63;
    int r = (t0 + tl)*B_ + b0 + bl;
    float p  = pT[r];
    float wu = wuT[r], wd = wdT[r];
    float4 k4 = *(const float4*)&pk4[(size_t)r*4];
    float ps = p - k4.x*wu*wu - k4.y*wd*wd;
    float runoff = hside(ps)*ps;
    tile[bl*65 + tl] = k4.z * runoff;
  }
  __syncthreads();
  #pragma unroll
  for (int k = 0; k < 16; ++k){
    int idx = k*256 + tid;
    int tl2 = idx & 63, bl2 = idx >> 6;
    out[(size_t)(b0 + bl2)*T_ + t0 + tl2] = tile[bl2*65 + tl2];
  }
}

extern "C" void kernel_launch(void* const* d_in, const int* in_sizes, int n_in,
                              void* d_out, int out_size, void* d_ws, size_t ws_size,
                              hipStream_t stream) {
  const float* in = (const float*)d_in[0];
  const float* w1 = (const float*)d_in[1];
  const float* b1 = (const float*)d_in[2];
  const float* w2 = (const float*)d_in[3];
  const float* b2 = (const float*)d_in[4];
  const float* w3 = (const float*)d_in[5];
  const float* b3 = (const float*)d_in[6];
  float* out = (float*)d_out;
  float* ws  = (float*)d_ws;

  fused_kernel<<<516, 512, 0, stream>>>(in, w1, b1, w2, b2, w3, b3, ws);
  final_kernel<<<128, 256, 0, stream>>>(ws, out);
}

// Round 11
// 224.422 us; speedup vs baseline: 1.6769x; 1.3451x over previous
//
#include <hip/hip_runtime.h>

#define B_ 256
#define T_ 2048
#define F_ 20
#define NT (B_*T_)
#define CH 16
#define NCH (T_/CH)   // 128 chunks

typedef __bf16 bf16x8 __attribute__((ext_vector_type(8)));
typedef float  f32x4  __attribute__((ext_vector_type(4)));

__device__ __forceinline__ float ex2(float x){ return __builtin_amdgcn_exp2f(x); }
__device__ __forceinline__ float rcpf_(float x){ return __builtin_amdgcn_rcpf(x); }

// 20*log2(e), 2*log2(e), log2(e), ln2/20
#define K10F 28.853900817779268f
#define INVK 0.034657359027997264f
#define K1F   2.8853900817779268f
#define LOG2E 1.4426950408889634f

__device__ __forceinline__ float hside(float x){ return 1.0f - rcpf_(ex2(K10F*x) + 1.0f); }
__device__ __forceinline__ float tanh_f(float z){ return 1.0f - 2.0f*rcpf_(ex2(K1F*z) + 1.0f); }
__device__ __forceinline__ float sigmoid_f(float z){ return rcpf_(1.0f + ex2(-LOG2E*z)); }

// ws float layout (t-major r = t*256 + b):
// pp2 [0,2NT) float2{pet,p} | wuT [2NT,3NT) | wdT [3NT,4NT) | pk4 [4NT,8NT) float4{A,B,KP,_}

// Streaming transpose: block = 16-b x 128-t tile. Reads: 16 sequential 80B-row
// streams (DRAM-friendly). Writes: 16 consecutive b per t = 128B full-line
// t-major segments (no RMW). Grid 16 x 16 = 256 blocks.
__global__ __launch_bounds__(256) void prep_kernel(const float* __restrict__ in,
                                                   float* __restrict__ ws){
  int bt = blockIdx.x & 15;      // b-tile
  int tt = blockIdx.x >> 4;      // t-tile
  int b0 = bt*16, t0 = tt*128;
  int bl = threadIdx.x & 15;     // b within tile
  int tw = threadIdx.x >> 4;     // t sub-lane [0,16)
  int b  = b0 + bl;
  const float* rowb = in + (size_t)b*T_*F_;
  float2* pp2 = (float2*)ws;
  #pragma unroll
  for (int k = 0; k < 8; ++k){
    int t = t0 + k*16 + tw;
    float4 r4 = *(const float4*)(rowb + (size_t)t*F_);
    pp2[t*B_ + b] = make_float2(r4.x, r4.z);   // pet, p
  }
}

// blocks 0..3: pipelined scan (64 batches each, 4 pipeline waves) — R3 structure,
// K-scaled arithmetic + hoisted prefetch.
// blocks 4..4099: MFMA MLP (128 rows each) + pk4 epilogue (R8-verbatim)
__global__ __launch_bounds__(512) void fused_kernel(const float* __restrict__ in,
    const float* __restrict__ w1, const float* __restrict__ b1,
    const float* __restrict__ w2, const float* __restrict__ b2,
    const float* __restrict__ w3, const float* __restrict__ b3,
    float* __restrict__ ws){
  extern __shared__ char sm[];
  float* pk4 = ws + 4*(size_t)NT;

  if (blockIdx.x < 4) {
    // ================== pipelined Xinanjiang scan (K-scaled) ==================
    asm volatile("s_setprio 3");
    const float2* pp2 = (const float2*)ws;
    float* wuT = ws + 2*(size_t)NT;
    float* wdT = ws + 3*(size_t)NT;
    float*  d1L = (float*)sm;                  // [2][CH][64]   8 KB   dK
    float*  bsQ = (float*)(sm + 8192);         // [4][CH][64]  16 KB   BASE
    float2* rhL = (float2*)(sm + 24576);       // [2][CH][64]  16 KB   {RP,HRP}
    float2* qbL = (float2*)(sm + 40960);       // [2][CH][64]  16 KB   {QV,B2}

    int tid = threadIdx.x;
    int wv = tid >> 6, lane = tid & 63;
    int boff = blockIdx.x * 64;

    if (wv == 0){
      // -------- wu chain (K-scaled) + hoisted pp2 prefetch + wuT stores --------
      float2 buf[CH], nbuf[CH];
      #pragma unroll
      for (int s = 0; s < CH; ++s) buf[s] = pp2[s*B_ + boff + lane];
      float Wu = 0.0f;
      for (int it = 0; it < NCH + 3; ++it){
        if (it < NCH){
          int c = it, par = c & 1;
          if (c + 1 < NCH){                     // prefetch FIRST: chain hides latency
            #pragma unroll
            for (int s = 0; s < CH; ++s) nbuf[s] = pp2[((c+1)*CH + s)*B_ + boff + lane];
          }
          #pragma unroll
          for (int s = 0; s < CH; ++s){
            float PET = K10F*buf[s].x;                 // off-chain
            float PPd = K10F*(buf[s].y - buf[s].x);    // off-chain
            float t1  = Wu - PET;
            float r   = rcpf_(ex2(t1) + 1.0f);
            float dK  = -t1*r;
            float BS  = PPd + dK;
            float WuPP= Wu + PPd;                      // off-chain
            Wu = fmaf(-t1, r, WuPP);
            d1L[par*(CH*64) + s*64 + lane] = dK;
            bsQ[(c&3)*(CH*64) + s*64 + lane] = BS;
            wuT[(c*CH + s)*B_ + boff + lane] = Wu * INVK;
          }
          if (c + 1 < NCH){
            #pragma unroll
            for (int s = 0; s < CH; ++s) buf[s] = nbuf[s];
          }
        }
        __syncthreads();
      }
      return;
    } else if (wv == 1){
      // -------- stateless RP/HRP (K-scaled) --------
      for (int it = 0; it < NCH + 3; ++it){
        if (it >= 1 && it <= NCH){
          int c = it - 1, par = c & 1;
          #pragma unroll
          for (int s = 0; s < CH; ++s){
            float dK = d1L[par*(CH*64) + s*64 + lane];
            float r2 = rcpf_(ex2(dK) + 1.0f);
            float RP = fmaf(-dK, r2, dK);
            float HRP = 1.0f - rcpf_(ex2(RP) + 1.0f);
            rhL[par*(CH*64) + s*64 + lane] = make_float2(RP, HRP);
          }
        }
        __syncthreads();
      }
      return;
    } else if (wv == 2){
      // -------- wl chain (K-scaled) --------
      float WL = 0.0f;
      for (int it = 0; it < NCH + 3; ++it){
        if (it >= 2 && it <= NCH + 1){
          int c = it - 2, par = c & 1;
          #pragma unroll
          for (int s = 0; s < CH; ++s){
            float2 rh  = rhL[par*(CH*64) + s*64 + lane];
            float BS   = bsQ[(c&3)*(CH*64) + s*64 + lane];
            float D2   = rh.x - WL;
            float r    = rcpf_(ex2(D2) + 1.0f);
            float et22 = fmaf(D2, r, WL);
            float ET2  = rh.y * et22;
            float WLB  = WL + BS;                      // off-chain
            WL = fmaf(-rh.y, et22, WLB);
            qbL[par*(CH*64) + s*64 + lane] = make_float2(rh.x - ET2, BS - ET2);
          }
        }
        __syncthreads();
      }
      return;
    } else if (wv == 3){
      // -------- wd chain (K-scaled) + wdT stores --------
      float WD = 0.0f;
      for (int it = 0; it < NCH + 3; ++it){
        if (it >= 3){
          int c = it - 3, par = c & 1;
          #pragma unroll
          for (int s = 0; s < CH; ++s){
            float2 qb  = qbL[par*(CH*64) + s*64 + lane];
            float HQ   = 1.0f - rcpf_(ex2(qb.x) + 1.0f);  // off-chain
            float D3   = qb.x - WD;
            float r    = rcpf_(ex2(D3) + 1.0f);
            float et33 = fmaf(D3, r, WD);
            float WDB  = WD + qb.y;                       // off-chain
            WD = fmaf(-HQ, et33, WDB);
            wdT[(c*CH + s)*B_ + boff + lane] = WD * INVK;
          }
        }
        __syncthreads();
      }
      return;
    } else {
      for (int it = 0; it < NCH + 3; ++it) __syncthreads();
      return;
    }
  }

  // ================== MFMA MLP path (R8-verbatim) ==================
  __bf16* w1f  = (__bf16*)sm;                // 8192 B
  __bf16* w2f  = (__bf16*)(sm + 8192);       // 32768 B
  float*  b1s  = (float*)(sm + 40960);
  float*  b2s  = (float*)(sm + 41984);
  float*  w3s  = (float*)(sm + 42240);
  float*  b3s  = (float*)(sm + 44288);
  __bf16* hbufA= (__bf16*)(sm + 44320);      // 8 waves × 16×72 bf16

  int tid = threadIdx.x;

  for (int s = tid; s < 16*32*8; s += 512) w1f[s] = (__bf16)0.0f;
  __syncthreads();
  for (int idx = tid; idx < 15*256; idx += 512){   // w1: (k,n) k<15
    int k = idx >> 8, n = idx & 255;
    int ct = n >> 4;
    int l  = ((k>>3)*16) + (n & 15);
    int j  = k & 7;
    w1f[(ct*32 + l)*8 + j] = (__bf16)w1[idx];
  }
  for (int idx = tid; idx < 256*64; idx += 512){   // w2: (k,n)
    int k = idx >> 6, n = idx & 63;
    int kb = k >> 5;
    int lq = (k >> 3) & 3;
    int j  = k & 7;
    int ct = n >> 4;
    int l  = lq*16 + (n & 15);
    w2f[((kb*4 + ct)*64 + l)*8 + j] = (__bf16)w2[idx];
  }
  if (tid < 256) b1s[tid] = b1[tid];
  if (tid < 64)  b2s[tid] = b2[tid];
  if (tid < 512) w3s[tid] = w3[tid];
  if (tid < 8)   b3s[tid] = b3[tid];
  __syncthreads();

  int lane = tid & 63;
  int wv   = tid >> 6;
  int m    = lane & 15;
  int q    = lane >> 4;
  int r0   = (blockIdx.x - 4)*128 + wv*16;   // t-major r

  int rowA = r0 + m;
  int bA = rowA & (B_-1), tA = rowA >> 8;
  const float* ap = in + ((size_t)bA*T_ + tA)*F_ + 5;
  bf16x8 a1;
  #pragma unroll
  for (int j = 0; j < 8; ++j){
    int k = q*8 + j;
    float v = (k < 15) ? ap[k] : 0.0f;
    a1[j] = (__bf16)v;
  }

  __bf16* hb = hbufA + wv*1152;
  f32x4 zero4 = {0.0f, 0.0f, 0.0f, 0.0f};
  bf16x8 zero8;
  #pragma unroll
  for (int j = 0; j < 8; ++j) zero8[j] = (__bf16)0.0f;

  f32x4 acc2[4] = {zero4, zero4, zero4, zero4};

  #pragma unroll
  for (int p = 0; p < 4; ++p){
    #pragma unroll
    for (int c4 = 0; c4 < 4; ++c4){
      int ct = p*4 + c4;
      bf16x8 bw = zero8;
      if (lane < 32) bw = *(const bf16x8*)&w1f[(ct*32 + lane)*8];
      f32x4 c1 = __builtin_amdgcn_mfma_f32_16x16x32_bf16(a1, bw, zero4, 0, 0, 0);
      int f = c4*16 + m;
      float bb = b1s[p*64 + f];
      #pragma unroll
      for (int i = 0; i < 4; ++i){
        float h = tanh_f(c1[i] + bb);
        hb[(q*4 + i)*72 + f] = (__bf16)h;
      }
    }
    #pragma unroll
    for (int kb = 0; kb < 2; ++kb){
      bf16x8 a2 = *(const bf16x8*)&hb[m*72 + q*8 + kb*32];
      #pragma unroll
      for (int ct = 0; ct < 4; ++ct){
        bf16x8 bw2 = *(const bf16x8*)&w2f[(((p*2 + kb)*4 + ct)*64 + lane)*8];
        acc2[ct] = __builtin_amdgcn_mfma_f32_16x16x32_bf16(a2, bw2, acc2[ct], 0, 0, 0);
      }
    }
  }

  #pragma unroll
  for (int ct = 0; ct < 4; ++ct){
    int f = ct*16 + m;
    float bb = b2s[f];
    #pragma unroll
    for (int i = 0; i < 4; ++i){
      float h = tanh_f(acc2[ct][i] + bb);
      hb[(q*4 + i)*72 + f] = (__bf16)h;
    }
  }

  float z0 = b3s[2*q], z1 = b3s[2*q + 1];
  #pragma unroll
  for (int kb3 = 0; kb3 < 8; ++kb3){
    bf16x8 hv8 = *(const bf16x8*)&hb[m*72 + kb3*8];
    #pragma unroll
    for (int j = 0; j < 8; ++j){
      float hv = (float)hv8[j];
      int k = kb3*8 + j;
      z0 = fmaf(hv, w3s[k*8 + 2*q],     z0);
      z1 = fmaf(hv, w3s[k*8 + 2*q + 1], z1);
    }
  }

  // reduce 8 params -> {A, B, KP} per row
  float* hf = (float*)hb;
  hf[m*8 + 2*q]     = sigmoid_f(z0);
  hf[m*8 + 2*q + 1] = sigmoid_f(z1);
  if (q == 0){
    float P0=hf[m*8+0], P1=hf[m*8+1], P2=hf[m*8+2], P3=hf[m*8+3];
    float P4=hf[m*8+4], P5=hf[m*8+5], P6=hf[m*8+6], P7=hf[m*8+7];
    // reference arg swap: _runoff(wu, wd, wl, p, wum, wdm, wlm, b, c)
    float wum = fmaf(P0, 19.9f, 0.1f);
    float wlm = fmaf(P2, 30.0f, 60.0f);
    float wdm = fmaf(P1, 60.0f, 60.0f);
    float wt  = wum + wlm + wdm;
    float rw  = 1.0f / wt;
    float cc  = fmaf(P4, 0.19f, 0.01f);
    float bc  = fmaf(P3, 0.30f, 0.10f);
    float A   = cc*rw*rw;
    float Bc  = bc*rw*rw;
    float k1  = fmaf(P5, 0.69f, 0.01f);
    float k2  = fmaf(P6, 0.69f, 0.01f);
    float k3  = fmaf(P7, 0.89f, 0.01f);
    float KP  = k1 + 0.5f*k2*(1.0f-k1) + 0.25f*k3*(1.0f-k1)*(1.0f-k2);
    int rowO = r0 + m;
    *(float4*)&pk4[(size_t)rowO*4] = make_float4(A, Bc, KP, 0.0f);
  }
}

// 64t × 64b tile; coalesced reads of t-major arrays, LDS transpose, coalesced out-writes
__global__ __launch_bounds__(256) void final_kernel(const float* __restrict__ ws,
                                                    float* __restrict__ out){
  __shared__ float tile[64*65];
  int tb = blockIdx.x & 31;
  int bb = blockIdx.x >> 5;
  int t0 = tb*64, b0 = bb*64;
  int tid = threadIdx.x;
  const float2* pp2 = (const float2*)ws;
  const float* wuT  = ws + 2*(size_t)NT;
  const float* wdT  = ws + 3*(size_t)NT;
  const float* pk4  = ws + 4*(size_t)NT;

  #pragma unroll
  for (int k = 0; k < 16; ++k){
    int idx = k*256 + tid;
    int tl = idx >> 6, bl = idx & 63;
    int r = (t0 + tl)*B_ + b0 + bl;
    float p  = pp2[r].y;
    float wu = wuT[r], wd = wdT[r];
    float4 k4 = *(const float4*)&pk4[(size_t)r*4];
    float ps = p - k4.x*wu*wu - k4.y*wd*wd;
    float runoff = hside(ps)*ps;
    tile[bl*65 + tl] = k4.z * runoff;
  }
  __syncthreads();
  #pragma unroll
  for (int k = 0; k < 16; ++k){
    int idx = k*256 + tid;
    int tl2 = idx & 63, bl2 = idx >> 6;
    out[(size_t)(b0 + bl2)*T_ + t0 + tl2] = tile[bl2*65 + tl2];
  }
}

extern "C" void kernel_launch(void* const* d_in, const int* in_sizes, int n_in,
                              void* d_out, int out_size, void* d_ws, size_t ws_size,
                              hipStream_t stream) {
  const float* in = (const float*)d_in[0];
  const float* w1 = (const float*)d_in[1];
  const float* b1 = (const float*)d_in[2];
  const float* w2 = (const float*)d_in[3];
  const float* b2 = (const float*)d_in[4];
  const float* w3 = (const float*)d_in[5];
  const float* b3 = (const float*)d_in[6];
  float* out = (float*)d_out;
  float* ws  = (float*)d_ws;

  prep_kernel <<<256,        256, 0,     stream>>>(in, ws);
  fused_kernel<<<NT/128 + 4, 512, 62752, stream>>>(in, w1, b1, w2, b2, w3, b3, ws);
  final_kernel<<<128,        256, 0,     stream>>>(ws, out);
}